// Round 7
// baseline (3235.145 us; speedup 1.0000x reference)
//
#include <hip/hip_runtime.h>

namespace {

constexpr int kT = 256;

typedef float f2 __attribute__((ext_vector_type(2)));
typedef float f4 __attribute__((ext_vector_type(4)));

__device__ __forceinline__ float fast_tanh(float x) {
    float e = __expf(2.0f * x);
    return 1.0f - 2.0f * __builtin_amdgcn_rcpf(e + 1.0f);
}

__device__ __forceinline__ float dpp_xor1(float x) {
    return __builtin_bit_cast(float, __builtin_amdgcn_update_dpp(
        0, __builtin_bit_cast(int, x), 0xB1, 0xF, 0xF, true)); // quad [1,0,3,2]
}
__device__ __forceinline__ float dpp_xor2(float x) {
    return __builtin_bit_cast(float, __builtin_amdgcn_update_dpp(
        0, __builtin_bit_cast(int, x), 0x4E, 0xF, 0xF, true)); // quad [2,3,0,1]
}
__device__ __forceinline__ float dpp_ror8(float x) {           // lane ^ 8 within row16
    return __builtin_bit_cast(float, __builtin_amdgcn_update_dpp(
        0, __builtin_bit_cast(int, x), 0x128, 0xF, 0xF, true)); // row_ror:8
}
template <int PAT>
__device__ __forceinline__ float swz(float x) {
    return __builtin_bit_cast(float,
        __builtin_amdgcn_ds_swizzle(__builtin_bit_cast(int, x), PAT));
}
__device__ __forceinline__ float read_lane(float x, int lane) {
    return __builtin_bit_cast(float,
        __builtin_amdgcn_readlane(__builtin_bit_cast(int, x), lane));
}

// h storage (2 rows): element (k, r) at float offset 4*(k>>1) + 4*(k>>3)
// + 2*r + (k&1). One f4 at a k-pair yields (k_e,r0),(k_o,r0),(k_e,r1),(k_o,r1)
// -> contiguous f2 halves feed v_pk_fma directly. Pad 4*(k>>3) spreads the
// 16 kc read-bases across banks (2-way max = free).
// NOTE: this f2-pair core family is the verified non-spilling structure
// (112-116 VGPR, r0/r3/r6). The r-major f4-quad core spills to scratch at ANY
// launch bounds (r1/r2/r5: pinned 128 VGPR + 59 GB FETCH/dispatch). Don't re-land.
__device__ __forceinline__ int haddr(int k, int r) {
    return 4 * (k >> 1) + 4 * (k >> 3) + 2 * r + (k & 1);
}

// 2 rows/block, 512 blocks = 2 blocks/CU = 4 waves/SIMD (needs VGPR <= 128,
// enforced by launch_bounds; this core measures ~112). Independent blocks
// overlap each other's barrier stalls on the CU.
__global__ __launch_bounds__(512, 2) void hybrid_ode_kernel(
    const float* __restrict__ y0,
    const float* __restrict__ t_span,
    const float* __restrict__ meal,
    const float* __restrict__ tvns,
    const float* __restrict__ W_in, const float* __restrict__ b_in,
    const float* __restrict__ W_h,  const float* __restrict__ b_h,
    const float* __restrict__ W_out,const float* __restrict__ b_out,
    float* __restrict__ out)
{
    const int tid = threadIdx.x;
    const int w   = tid >> 6;          // wave 0..7
    const int l   = tid & 63;
    const int jgl = l >> 4;            // 0..3 j-group within wave
    const int kc  = l & 15;            // k-chunk (8 k's)
    const int kmid = (kc >> 1) & 3;    // kc bits 1..2 (j-XOR key, uniform stages)
    const int jg  = w * 4 + jgl;       // 0..31
    const int jb  = jg * 4;            // thread's 4 j's: jb..jb+3 (XOR-permuted)
    const int rw  = w & 1;             // batch row this wave carries (0/1)
    const int row = blockIdx.x * 2 + rw;

    // produced output slot after reduce-scatter: r_p = kc&1, j_p = jb + kmid,
    // duplicated across kc-bit3 (both lanes write same value/addr, benign).
    const int r_p = kc & 1;
    const int j_p = jb + kmid;
    const int waddr = haddr(j_p, r_p);
    const bool pb0 = (kc & 1) != 0;

    __shared__ __align__(16) float hp0[320];
    __shared__ __align__(16) float hp1[320];

    // ---- one-time weight staging into registers
    // wgt[ll][ka][jj] holds column j = jb + (jj ^ kmid): the j-XOR makes
    // butterfly stages for kc-bits 1/2 uniform (no keep/give selects).
    f2 wgt[3][4][4];   // [layer][kpair ka][jj]: k = 8kc+2*ka (+1)
    #pragma unroll
    for (int ll = 0; ll < 3; ++ll)
        #pragma unroll
        for (int ka = 0; ka < 4; ++ka)
            #pragma unroll
            for (int jj = 0; jj < 4; ++jj) {
                const float* p = W_h + (size_t)(ll * 128 + 8 * kc + 2 * ka) * 128
                               + jb + (jj ^ kmid);
                f2 v; v.x = p[0]; v.y = p[128];
                wgt[ll][ka][jj] = v;
            }

    // Input layer is register-direct: waves 0..3 produce h0; wave w covers
    // row rw = w&1, columns j2 = l + 64*((w>>1)&1). x-vector is wave-uniform
    // in registers. The two y3 terms (k=4, k=7) fold into one staged weight.
    const int j2 = l + 64 * ((w >> 1) & 1);
    const int waddr2 = haddr(j2, rw);
    float win[8];
    win[0] = W_in[0 * 128 + j2];                         // t
    win[1] = W_in[1 * 128 + j2];                         // y0
    win[2] = W_in[2 * 128 + j2];                         // y1
    win[3] = W_in[3 * 128 + j2];                         // y2
    win[4] = W_in[4 * 128 + j2] + W_in[7 * 128 + j2];    // y3 (+ glp1=y3)
    win[5] = W_in[5 * 128 + j2];                         // y4
    win[6] = W_in[6 * 128 + j2];                         // y5
    win[7] = W_in[8 * 128 + j2];                         // v
    const float bin = b_in[j2];

    float bh[3];
    #pragma unroll
    for (int ll = 0; ll < 3; ++ll) bh[ll] = b_h[ll * 128 + j_p];

    // output layer: XOR-permuted weights for a 3-bit reduce-scatter (s lands at l&7)
    const int s8 = l & 7;
    float wo0p[8], wo1p[8], bo[6];
    #pragma unroll
    for (int p = 0; p < 8; ++p) {
        const int q = p ^ s8;
        wo0p[p] = (q < 6) ? W_out[l * 6 + q] : 0.0f;
        wo1p[p] = (q < 6) ? W_out[(l + 64) * 6 + q] : 0.0f;
    }
    #pragma unroll
    for (int s = 0; s < 6; ++s) bo[s] = b_out[s];
    const int oaddrA = haddr(l, 0);        // + 2*rw at use
    const int oaddrB = haddr(l + 64, 0);   // = oaddrA + 160

    float y[6];
    #pragma unroll
    for (int s = 0; s < 6; ++s) y[s] = y0[row * 6 + s];

    if (w < 2 && l == 0) {
        #pragma unroll
        for (int s = 0; s < 6; ++s) out[(size_t)row * kT * 6 + s] = y[s];
    }

    const float* mrow = meal + (size_t)row * kT;
    const float* vrow = tvns + (size_t)row * kT;

    auto dyn = [&](float t, const float* yc, float m, float v, float* d) {
        // ---- input layer 9->128, register-direct; waves 0..3 cover all
        // 256 (row, j) slots. Prior hp0 readers (layer-3) are ordered by the
        // post-L3 barrier of the previous dyn.
        if (w < 4) {
            float s = bin + t * win[0];
            s += yc[0] * win[1] + yc[1] * win[2] + yc[2] * win[3];
            s += yc[3] * win[4] + yc[4] * win[5] + yc[5] * win[6];
            s += v * win[7];
            hp0[waddr2] = fast_tanh(s);
        }
        __syncthreads();

        // ---- 3 hidden layers 128->128 (both rows in the accumulator)
        #pragma unroll
        for (int ll = 0; ll < 3; ++ll) {
            const float* rb = (ll & 1) ? hp1 : hp0;
            float*       wb = (ll & 1) ? hp0 : hp1;

            // 4x ds_read_b128: q = (k_e,r0),(k_o,r0),(k_e,r1),(k_o,r1)
            const float* hb = rb + 20 * kc;
            f2 acc[4][2];   // [jj][r], packed over k-parity
            #pragma unroll
            for (int ka = 0; ka < 4; ++ka) {
                f4 q = *(const f4*)(hb + 4 * ka);
                f2 h0 = __builtin_shufflevector(q, q, 0, 1);   // row 0
                f2 h1 = __builtin_shufflevector(q, q, 2, 3);   // row 1
                #pragma unroll
                for (int jj = 0; jj < 4; ++jj) {
                    const f2 wv = wgt[ll][ka][jj];
                    if (ka == 0) {
                        acc[jj][0] = h0 * wv;
                        acc[jj][1] = h1 * wv;
                    } else {
                        acc[jj][0] = h0 * wv + acc[jj][0];
                        acc[jj][1] = h1 * wv + acc[jj][1];
                    }
                }
            }

            // horizontal add over k-parity; A indexed o = (jj<<1)|r,
            // value is column j = jb + (jj ^ kmid), row r.
            float A[8];
            #pragma unroll
            for (int o = 0; o < 8; ++o)
                A[o] = acc[o >> 1][o & 1].x + acc[o >> 1][o & 1].y;

            // Reduce-scatter over 16 kc lanes:
            //  stage kc-bit0 <-> r (keep/give selects), stages kc-bit1/2 <->
            //  jj bits (uniform via the jj^kmid perm), stage kc-bit3 is a
            //  both-keep duplicate-sum (each half holds 64 of the 128 k's).
            float B[4];
            #pragma unroll
            for (int i = 0; i < 4; ++i) {
                float keep = pb0 ? A[2*i+1] : A[2*i];
                float give = pb0 ? A[2*i]   : A[2*i+1];
                B[i] = keep + dpp_xor1(give);
            }
            float C[2];
            #pragma unroll
            for (int i = 0; i < 2; ++i)
                C[i] = B[2*i] + dpp_xor2(B[2*i+1]);   // uniform
            float S = C[0] + swz<0x101F>(C[1]);        // xor4, uniform
            S += dpp_ror8(S);                          // xor8 duplicate-sum

            wb[waddr] = fast_tanh(S + bh[ll]);
            __syncthreads();
        }

        // ---- output layer 128->6 for this wave's row; h3 lives in hp1.
        // Reduce-scatter s to lane s8 (uniform, XOR'd weights), all-reduce
        // the 8-lane groups, then readlane-broadcast p[0..5] as wave scalars.
        const float hA = hp1[oaddrA + 2 * rw];
        const float hB = hp1[oaddrB + 2 * rw];
        float P[8];
        #pragma unroll
        for (int p = 0; p < 8; ++p) P[p] = hA * wo0p[p] + hB * wo1p[p];
        float Q[4];
        #pragma unroll
        for (int i = 0; i < 4; ++i) Q[i] = P[2*i] + dpp_xor1(P[2*i+1]);
        const float R0 = Q[0] + dpp_xor2(Q[1]);
        const float R1 = Q[2] + dpp_xor2(Q[3]);
        float S = R0 + swz<0x101F>(R1);   // xor4
        S += dpp_ror8(S);                 // xor8
        S += swz<0x401F>(S);              // xor16
        S += __shfl_xor(S, 32);           // xor32

        const float p0 = read_lane(S, 0);
        const float p1 = read_lane(S, 1);
        const float p2 = read_lane(S, 2);
        const float p3 = read_lane(S, 3);
        const float p4 = read_lane(S, 4);
        const float p5 = read_lane(S, 5);

        const float G = yc[0], I = yc[1], N = yc[2], L = yc[3], GE = yc[4], F = yc[5];
        d[0] = -0.01f*I*G + 0.05f*GE                                    + p0 + bo[0];
        d[1] = (G/(100.0f+G))*(1.0f + 2.0f*L/(5.0f+L)) - 0.1f*I         + p1 + bo[1];
        d[2] = -0.05f*N                                                 + p2 + bo[2];
        d[3] = 0.05f*GE - 0.2f*L                                        + p3 + bo[3];
        d[4] = m - 0.05f*GE                                             + p4 + bo[4];
        d[5] = -0.01f*I*F                                               + p5 + bo[5];
    };

    for (int i = 0; i < kT - 1; ++i) {
        const float t0 = t_span[i], t1 = t_span[i + 1];
        const float dt = t1 - t0;
        const float m0 = mrow[i], m1 = mrow[i + 1];
        const float v0 = vrow[i], v1 = vrow[i + 1];
        const float tm = t0 + 0.5f * dt;
        const float mm = 0.5f * (m0 + m1), vm = 0.5f * (v0 + v1);

        float d[6], ksum[6], yc[6];

        dyn(t0, y, m0, v0, d);
        #pragma unroll
        for (int s = 0; s < 6; ++s) { ksum[s] = d[s]; yc[s] = y[s] + 0.5f * dt * d[s]; }
        dyn(tm, yc, mm, vm, d);
        #pragma unroll
        for (int s = 0; s < 6; ++s) { ksum[s] += 2.0f * d[s]; yc[s] = y[s] + 0.5f * dt * d[s]; }
        dyn(tm, yc, mm, vm, d);
        #pragma unroll
        for (int s = 0; s < 6; ++s) { ksum[s] += 2.0f * d[s]; yc[s] = y[s] + dt * d[s]; }
        dyn(t1, yc, m1, v1, d);
        #pragma unroll
        for (int s = 0; s < 6; ++s) {
            ksum[s] += d[s];
            y[s] += (dt * (1.0f / 6.0f)) * ksum[s];
        }

        if (w < 2 && l == 0) {
            #pragma unroll
            for (int s = 0; s < 6; ++s)
                out[((size_t)row * kT + (i + 1)) * 6 + s] = y[s];
        }
    }
}

} // namespace

extern "C" void kernel_launch(void* const* d_in, const int* in_sizes, int n_in,
                              void* d_out, int out_size, void* d_ws, size_t ws_size,
                              hipStream_t stream) {
    const float* y0     = (const float*)d_in[0];
    const float* t_span = (const float*)d_in[1];
    const float* meal   = (const float*)d_in[2];
    const float* tvns   = (const float*)d_in[3];
    const float* W_in   = (const float*)d_in[4];
    const float* b_in   = (const float*)d_in[5];
    const float* W_h    = (const float*)d_in[6];
    const float* b_h    = (const float*)d_in[7];
    const float* W_out  = (const float*)d_in[8];
    const float* b_out  = (const float*)d_in[9];
    float* out          = (float*)d_out;

    hipLaunchKernelGGL(hybrid_ode_kernel, dim3(512), dim3(512), 0, stream,
                       y0, t_span, meal, tvns,
                       W_in, b_in, W_h, b_h, W_out, b_out, out);
}